// Round 1
// baseline (636.358 us; speedup 1.0000x reference)
//
#include <hip/hip_runtime.h>
#include <hip/hip_bf16.h>

#define N_NODES 50000
#define N_EDGES 800000
#define D_FEAT 128
#define HEADS 8
#define UNITS 32
#define HU (HEADS * UNITS) /* 256 */
#define LEAKY 0.2f
#define EPSV 1e-7f
#define NPB 16 /* nodes per block in GEMM */

// ---- order-preserving float<->uint transform for atomicMax on floats ----
__device__ __forceinline__ unsigned f2ord(float fv) {
    unsigned u = __float_as_uint(fv);
    return (u & 0x80000000u) ? ~u : (u | 0x80000000u);
}
__device__ __forceinline__ float ord2f(unsigned u) {
    return __uint_as_float((u & 0x80000000u) ? (u & 0x7fffffffu) : ~u);
}

// ---- GEMM: h = x @ W  (50000x128 @ 128x256), fused f = sum(h*ka1, units) ----
__global__ __launch_bounds__(256) void k_gemm(const float* __restrict__ x,
                                              const float* __restrict__ W,
                                              const float* __restrict__ ka1,
                                              float* __restrict__ h,
                                              float* __restrict__ f) {
    __shared__ float xs[NPB * D_FEAT]; // 8 KB
    const int t = threadIdx.x;         // output column 0..255
    const int nb = blockIdx.x * NPB;

    for (int idx = t; idx < NPB * D_FEAT; idx += 256)
        xs[idx] = x[nb * D_FEAT + idx];
    __syncthreads();

    float acc[NPB];
#pragma unroll
    for (int i = 0; i < NPB; ++i) acc[i] = 0.f;

#pragma unroll 4
    for (int k = 0; k < D_FEAT; ++k) {
        const float w = W[k * HU + t];
#pragma unroll
        for (int i = 0; i < NPB; ++i) acc[i] += xs[i * D_FEAT + k] * w;
    }

    const float a1 = ka1[t];
    const int head = t >> 5;   // which head this column belongs to
    const int l32 = t & 31;
#pragma unroll
    for (int i = 0; i < NPB; ++i) {
        h[(size_t)(nb + i) * HU + t] = acc[i];
        float p = acc[i] * a1;
        // reduce over the 32 unit-columns of this head (contiguous 32 lanes)
#pragma unroll
        for (int m = 16; m >= 1; m >>= 1) p += __shfl_xor(p, m);
        if (l32 == 0) f[(nb + i) * HEADS + head] = p;
    }
}

// ---- count in-degree per target ----
__global__ __launch_bounds__(256) void k_count(const int* __restrict__ edges,
                                               int* __restrict__ counts) {
    const int e = blockIdx.x * 256 + threadIdx.x;
    if (e >= N_EDGES) return;
    atomicAdd(&counts[edges[2 * e + 1]], 1);
}

// ---- single-block exclusive scan of counts -> offs (50000 elems) ----
#define SCAN_T 1024
#define CHUNK 49 /* 1024*49 = 50176 >= 50000 */
__global__ __launch_bounds__(1024) void k_scan(const int* __restrict__ counts,
                                               int* __restrict__ offs) {
    __shared__ int sdata[SCAN_T];
    const int t = threadIdx.x;
    const int base = t * CHUNK;
    int sum = 0;
    for (int i = 0; i < CHUNK; ++i) {
        const int idx = base + i;
        if (idx < N_NODES) sum += counts[idx];
    }
    sdata[t] = sum;
    __syncthreads();
    for (int o = 1; o < SCAN_T; o <<= 1) {
        const int v = (t >= o) ? sdata[t - o] : 0;
        __syncthreads();
        sdata[t] += v;
        __syncthreads();
    }
    int run = (t > 0) ? sdata[t - 1] : 0;
    for (int i = 0; i < CHUNK; ++i) {
        const int idx = base + i;
        if (idx < N_NODES) {
            offs[idx] = run;
            run += counts[idx];
        }
    }
}

// ---- fill CSR (src list + CSR-ordered raw scores), segment-max via atomicMax ----
__global__ __launch_bounds__(256) void k_fill(const int* __restrict__ edges,
                                              const float* __restrict__ f,
                                              int* __restrict__ offs, // used as cursors
                                              int* __restrict__ elist,
                                              float* __restrict__ slist,
                                              unsigned* __restrict__ segmax) {
    const int e = blockIdx.x * 256 + threadIdx.x;
    if (e >= N_EDGES) return;
    const int s = edges[2 * e];
    const int t = edges[2 * e + 1];
    const int t2 = edges[2 * s + 1]; // reference quirk: f_s = f[targets[sources[e]]]
    const int p = atomicAdd(&offs[t], 1);
    elist[p] = s;
#pragma unroll
    for (int hd = 0; hd < HEADS; ++hd) {
        const float z = f[t * HEADS + hd] + f[t2 * HEADS + hd];
        const float sc = (z > 0.f) ? z : LEAKY * z;
        slist[p * HEADS + hd] = sc;
        atomicMax(&segmax[t * HEADS + hd], f2ord(sc));
    }
}

// ---- per-node softmax + weighted gather-sum of h[src] rows, ELU epilogue ----
__global__ __launch_bounds__(64) void k_out(const float* __restrict__ h,
                                            const int* __restrict__ elist,
                                            const float* __restrict__ slist,
                                            const unsigned* __restrict__ segmax,
                                            const int* __restrict__ offs, // post-fill = segment END
                                            const int* __restrict__ counts,
                                            const float* __restrict__ bias,
                                            float* __restrict__ out) {
    const int n = blockIdx.x;
    const int lane = threadIdx.x;  // 0..63
    const int head = lane >> 3;    // 8 lanes per head, 4 channels per lane
    const int end = offs[n];
    const int cnt = counts[n];
    const int start = end - cnt;
    const float mx = ord2f(segmax[n * HEADS + head]);

    float den = 0.f;
    for (int p = start; p < end; ++p)
        den += __expf(slist[p * HEADS + head] - mx);
    den += EPSV;
    const float inv = 1.f / den;

    const int c4 = lane * 4;
    float4 acc = make_float4(0.f, 0.f, 0.f, 0.f);
    for (int p = start; p < end; ++p) {
        const float w = __expf(slist[p * HEADS + head] - mx) * inv;
        const int se = elist[p];
        const float4 hv = *reinterpret_cast<const float4*>(h + (size_t)se * HU + c4);
        acc.x += w * hv.x;
        acc.y += w * hv.y;
        acc.z += w * hv.z;
        acc.w += w * hv.w;
    }
    const float4 b = *reinterpret_cast<const float4*>(bias + c4);
    float v;
    float4 o;
    v = acc.x + b.x; o.x = (v > 0.f) ? v : expm1f(v);
    v = acc.y + b.y; o.y = (v > 0.f) ? v : expm1f(v);
    v = acc.z + b.z; o.z = (v > 0.f) ? v : expm1f(v);
    v = acc.w + b.w; o.w = (v > 0.f) ? v : expm1f(v);
    *reinterpret_cast<float4*>(out + (size_t)n * HU + c4) = o;
}

extern "C" void kernel_launch(void* const* d_in, const int* in_sizes, int n_in,
                              void* d_out, int out_size, void* d_ws, size_t ws_size,
                              hipStream_t stream) {
    const float* x = (const float*)d_in[0];
    const int* edges = (const int*)d_in[1];
    const float* W = (const float*)d_in[2];
    const float* ka1 = (const float*)d_in[3];
    // d_in[4] = ka2: unused by the reference
    const float* bias = (const float*)d_in[5];
    float* out = (float*)d_out;

    char* ws = (char*)d_ws;
    size_t off = 0;
    auto alloc = [&](size_t bytes) -> void* {
        void* p = ws + off;
        off = (off + bytes + 255) & ~size_t(255);
        return p;
    };
    float* h = (float*)alloc(sizeof(float) * (size_t)N_NODES * HU);     // 51.2 MB
    float* f = (float*)alloc(sizeof(float) * N_NODES * HEADS);          // 1.6 MB
    unsigned* segmax = (unsigned*)alloc(sizeof(unsigned) * N_NODES * HEADS);
    int* counts = (int*)alloc(sizeof(int) * N_NODES);
    int* offs = (int*)alloc(sizeof(int) * N_NODES);
    int* elist = (int*)alloc(sizeof(int) * N_EDGES);                    // 3.2 MB
    float* slist = (float*)alloc(sizeof(float) * (size_t)N_EDGES * HEADS); // 25.6 MB

    hipMemsetAsync(segmax, 0, sizeof(unsigned) * N_NODES * HEADS, stream);
    hipMemsetAsync(counts, 0, sizeof(int) * N_NODES, stream);

    k_gemm<<<N_NODES / NPB, 256, 0, stream>>>(x, W, ka1, h, f);
    k_count<<<(N_EDGES + 255) / 256, 256, 0, stream>>>(edges, counts);
    k_scan<<<1, SCAN_T, 0, stream>>>(counts, offs);
    k_fill<<<(N_EDGES + 255) / 256, 256, 0, stream>>>(edges, f, offs, elist, slist, segmax);
    k_out<<<N_NODES, 64, 0, stream>>>(h, elist, slist, segmax, offs, counts, bias, out);
}

// Round 2
// 398.502 us; speedup vs baseline: 1.5969x; 1.5969x over previous
//
#include <hip/hip_runtime.h>
#include <hip/hip_bf16.h>

#define N_NODES 50000
#define N_EDGES 800000
#define D_FEAT 128
#define HEADS 8
#define UNITS 32
#define HU (HEADS * UNITS) /* 256 */
#define LEAKY 0.2f
#define EPSV 1e-7f
#define NPB 16 /* nodes per block in GEMM */

// ---- GEMM: h = x @ W  (50000x128 @ 128x256), fused f = sum(h*ka1, units) ----
__global__ __launch_bounds__(256) void k_gemm(const float* __restrict__ x,
                                              const float* __restrict__ W,
                                              const float* __restrict__ ka1,
                                              float* __restrict__ h,
                                              float* __restrict__ f) {
    __shared__ float xs[NPB * D_FEAT]; // 8 KB
    const int t = threadIdx.x;         // output column 0..255
    const int nb = blockIdx.x * NPB;

    for (int idx = t; idx < NPB * D_FEAT; idx += 256)
        xs[idx] = x[nb * D_FEAT + idx];
    __syncthreads();

    float acc[NPB];
#pragma unroll
    for (int i = 0; i < NPB; ++i) acc[i] = 0.f;

#pragma unroll 4
    for (int k = 0; k < D_FEAT; ++k) {
        const float w = W[k * HU + t];
#pragma unroll
        for (int i = 0; i < NPB; ++i) acc[i] += xs[i * D_FEAT + k] * w;
    }

    const float a1 = ka1[t];
    const int head = t >> 5;
    const int l32 = t & 31;
#pragma unroll
    for (int i = 0; i < NPB; ++i) {
        h[(size_t)(nb + i) * HU + t] = acc[i];
        float p = acc[i] * a1;
#pragma unroll
        for (int m = 16; m >= 1; m >>= 1) p += __shfl_xor(p, m);
        if (l32 == 0) f[(nb + i) * HEADS + head] = p;
    }
}

// ---- g[v][hd] = f[targets[v]][hd]  (reference quirk: f_s = f_t[sources]) ----
__global__ __launch_bounds__(256) void k_g(const int* __restrict__ edges,
                                           const float* __restrict__ f,
                                           float* __restrict__ g) {
    const int v = blockIdx.x * 256 + threadIdx.x;
    if (v >= N_NODES) return;
    const int t2 = edges[2 * v + 1];
    const float4 a = *reinterpret_cast<const float4*>(f + (size_t)t2 * HEADS);
    const float4 b = *reinterpret_cast<const float4*>(f + (size_t)t2 * HEADS + 4);
    *reinterpret_cast<float4*>(g + (size_t)v * HEADS) = a;
    *reinterpret_cast<float4*>(g + (size_t)v * HEADS + 4) = b;
}

// ---- count in-degree per target ----
__global__ __launch_bounds__(256) void k_count(const int* __restrict__ edges,
                                               int* __restrict__ counts) {
    const int e = blockIdx.x * 256 + threadIdx.x;
    if (e >= N_EDGES) return;
    atomicAdd(&counts[edges[2 * e + 1]], 1);
}

// ---- single-block exclusive scan of counts -> offs (50000 elems) ----
#define SCAN_T 1024
#define CHUNK 49 /* 1024*49 = 50176 >= 50000 */
__global__ __launch_bounds__(1024) void k_scan(const int* __restrict__ counts,
                                               int* __restrict__ offs) {
    __shared__ int sdata[SCAN_T];
    const int t = threadIdx.x;
    const int base = t * CHUNK;
    int sum = 0;
    for (int i = 0; i < CHUNK; ++i) {
        const int idx = base + i;
        if (idx < N_NODES) sum += counts[idx];
    }
    sdata[t] = sum;
    __syncthreads();
    for (int o = 1; o < SCAN_T; o <<= 1) {
        const int v = (t >= o) ? sdata[t - o] : 0;
        __syncthreads();
        sdata[t] += v;
        __syncthreads();
    }
    int run = (t > 0) ? sdata[t - 1] : 0;
    for (int i = 0; i < CHUNK; ++i) {
        const int idx = base + i;
        if (idx < N_NODES) {
            offs[idx] = run;
            run += counts[idx];
        }
    }
}

// ---- fill CSR source list only (cursor atomics; offs becomes segment END) ----
__global__ __launch_bounds__(256) void k_fill(const int* __restrict__ edges,
                                              int* __restrict__ offs,
                                              int* __restrict__ elist) {
    const int e = blockIdx.x * 256 + threadIdx.x;
    if (e >= N_EDGES) return;
    const int s = edges[2 * e];
    const int t = edges[2 * e + 1];
    const int p = atomicAdd(&offs[t], 1);
    elist[p] = s;
}

// ---- per-node softmax (recomputed scores) + weighted gather of h rows ----
__global__ __launch_bounds__(64) void k_out(const float* __restrict__ h,
                                            const int* __restrict__ elist,
                                            const float* __restrict__ f,
                                            const float* __restrict__ g,
                                            const int* __restrict__ offs, // = segment END after fill
                                            const int* __restrict__ counts,
                                            const float* __restrict__ bias,
                                            float* __restrict__ out) {
    const int n = blockIdx.x;
    const int lane = threadIdx.x;  // 0..63
    const int head = lane >> 3;    // 8 lanes per head, 4 channels per lane
    const int end = offs[n];
    const int cnt = counts[n];
    const int start = end - cnt;
    const float fn = f[(size_t)n * HEADS + head];

    // pass 1: segment max (recompute scores from f/g)
    float mx = -INFINITY;
    for (int p = start; p < end; ++p) {
        const int s = elist[p];
        float z = fn + g[(size_t)s * HEADS + head];
        z = (z > 0.f) ? z : LEAKY * z;
        mx = fmaxf(mx, z);
    }

    // pass 2: denom + unnormalized weighted sum of h[src]
    const int c4 = lane * 4; // == head*32 + (lane&7)*4
    float den = 0.f;
    float4 acc = make_float4(0.f, 0.f, 0.f, 0.f);
    for (int p = start; p < end; ++p) {
        const int s = elist[p];
        float z = fn + g[(size_t)s * HEADS + head];
        z = (z > 0.f) ? z : LEAKY * z;
        const float w = __expf(z - mx);
        den += w;
        const float4 hv = *reinterpret_cast<const float4*>(h + (size_t)s * HU + c4);
        acc.x += w * hv.x;
        acc.y += w * hv.y;
        acc.z += w * hv.z;
        acc.w += w * hv.w;
    }
    den += EPSV;
    const float inv = 1.f / den;

    const float4 b = *reinterpret_cast<const float4*>(bias + c4);
    float v;
    float4 o;
    v = acc.x * inv + b.x; o.x = (v > 0.f) ? v : expm1f(v);
    v = acc.y * inv + b.y; o.y = (v > 0.f) ? v : expm1f(v);
    v = acc.z * inv + b.z; o.z = (v > 0.f) ? v : expm1f(v);
    v = acc.w * inv + b.w; o.w = (v > 0.f) ? v : expm1f(v);
    *reinterpret_cast<float4*>(out + (size_t)n * HU + c4) = o;
}

extern "C" void kernel_launch(void* const* d_in, const int* in_sizes, int n_in,
                              void* d_out, int out_size, void* d_ws, size_t ws_size,
                              hipStream_t stream) {
    const float* x = (const float*)d_in[0];
    const int* edges = (const int*)d_in[1];
    const float* W = (const float*)d_in[2];
    const float* ka1 = (const float*)d_in[3];
    // d_in[4] = ka2: unused by the reference
    const float* bias = (const float*)d_in[5];
    float* out = (float*)d_out;

    char* ws = (char*)d_ws;
    size_t off = 0;
    auto alloc = [&](size_t bytes) -> void* {
        void* p = ws + off;
        off = (off + bytes + 255) & ~size_t(255);
        return p;
    };
    float* h = (float*)alloc(sizeof(float) * (size_t)N_NODES * HU);  // 51.2 MB
    float* f = (float*)alloc(sizeof(float) * N_NODES * HEADS);       // 1.6 MB
    float* g = (float*)alloc(sizeof(float) * N_NODES * HEADS);       // 1.6 MB
    int* counts = (int*)alloc(sizeof(int) * N_NODES);
    int* offs = (int*)alloc(sizeof(int) * N_NODES);
    int* elist = (int*)alloc(sizeof(int) * N_EDGES);                 // 3.2 MB

    hipMemsetAsync(counts, 0, sizeof(int) * N_NODES, stream);

    k_gemm<<<N_NODES / NPB, 256, 0, stream>>>(x, W, ka1, h, f);
    k_g<<<(N_NODES + 255) / 256, 256, 0, stream>>>(edges, f, g);
    k_count<<<(N_EDGES + 255) / 256, 256, 0, stream>>>(edges, counts);
    k_scan<<<1, SCAN_T, 0, stream>>>(counts, offs);
    k_fill<<<(N_EDGES + 255) / 256, 256, 0, stream>>>(edges, offs, elist);
    k_out<<<N_NODES, 64, 0, stream>>>(h, elist, f, g, offs, counts, bias, out);
}

// Round 3
// 345.905 us; speedup vs baseline: 1.8397x; 1.1521x over previous
//
#include <hip/hip_runtime.h>
#include <hip/hip_fp16.h>

#define N_NODES 50000
#define N_EDGES 800000
#define D_FEAT 128
#define HEADS 8
#define UNITS 32
#define HU (HEADS * UNITS) /* 256 */
#define LEAKY 0.2f
#define EPSV 1e-7f
#define NPB 16 /* nodes per block in GEMM */

struct h4pk { __half2 a, b; }; // 4 fp16 channels = 8 bytes

// ---- GEMM: h = x @ W (fp16 out), fused f = sum(h*ka1, units) (fp32) ----
__global__ __launch_bounds__(256) void k_gemm(const float* __restrict__ x,
                                              const float* __restrict__ W,
                                              const float* __restrict__ ka1,
                                              __half* __restrict__ h,
                                              float* __restrict__ f) {
    __shared__ float xs[NPB * D_FEAT]; // 8 KB
    const int t = threadIdx.x;         // output column 0..255
    const int nb = blockIdx.x * NPB;

    for (int idx = t; idx < NPB * D_FEAT; idx += 256)
        xs[idx] = x[(size_t)nb * D_FEAT + idx];
    __syncthreads();

    float acc[NPB];
#pragma unroll
    for (int i = 0; i < NPB; ++i) acc[i] = 0.f;

#pragma unroll 4
    for (int k = 0; k < D_FEAT; k += 4) {
        const float w0 = W[(k + 0) * HU + t];
        const float w1 = W[(k + 1) * HU + t];
        const float w2 = W[(k + 2) * HU + t];
        const float w3 = W[(k + 3) * HU + t];
#pragma unroll
        for (int i = 0; i < NPB; ++i) {
            const float4 xv = *reinterpret_cast<const float4*>(&xs[i * D_FEAT + k]);
            acc[i] += xv.x * w0 + xv.y * w1 + xv.z * w2 + xv.w * w3;
        }
    }

    const float a1 = ka1[t];
    const int head = t >> 5;
    const int l32 = t & 31;
#pragma unroll
    for (int i = 0; i < NPB; ++i) {
        h[(size_t)(nb + i) * HU + t] = __float2half(acc[i]);
        float p = acc[i] * a1;
#pragma unroll
        for (int m = 16; m >= 1; m >>= 1) p += __shfl_xor(p, m);
        if (l32 == 0) f[(size_t)(nb + i) * HEADS + head] = p;
    }
}

// ---- fused: g[v] = f[targets[v]] (v<N_NODES) + in-degree count (e<N_EDGES) ----
__global__ __launch_bounds__(256) void k_pre(const int* __restrict__ edges,
                                             const float* __restrict__ f,
                                             float* __restrict__ g,
                                             int* __restrict__ counts) {
    const int i = blockIdx.x * 256 + threadIdx.x;
    if (i < N_NODES) {
        const int t2 = edges[2 * i + 1];
        const float4 a = *reinterpret_cast<const float4*>(f + (size_t)t2 * HEADS);
        const float4 b = *reinterpret_cast<const float4*>(f + (size_t)t2 * HEADS + 4);
        *reinterpret_cast<float4*>(g + (size_t)i * HEADS) = a;
        *reinterpret_cast<float4*>(g + (size_t)i * HEADS + 4) = b;
    }
    if (i < N_EDGES) atomicAdd(&counts[edges[2 * i + 1]], 1);
}

// ---- single-block exclusive scan of counts -> offs ----
#define SCAN_T 1024
#define CHUNK 49 /* 1024*49 = 50176 >= 50000 */
__global__ __launch_bounds__(1024) void k_scan(const int* __restrict__ counts,
                                               int* __restrict__ offs) {
    __shared__ int sdata[SCAN_T];
    const int t = threadIdx.x;
    const int base = t * CHUNK;
    int sum = 0;
    for (int i = 0; i < CHUNK; ++i) {
        const int idx = base + i;
        if (idx < N_NODES) sum += counts[idx];
    }
    sdata[t] = sum;
    __syncthreads();
    for (int o = 1; o < SCAN_T; o <<= 1) {
        const int v = (t >= o) ? sdata[t - o] : 0;
        __syncthreads();
        sdata[t] += v;
        __syncthreads();
    }
    int run = (t > 0) ? sdata[t - 1] : 0;
    for (int i = 0; i < CHUNK; ++i) {
        const int idx = base + i;
        if (idx < N_NODES) {
            offs[idx] = run;
            run += counts[idx];
        }
    }
}

// ---- fill CSR source list (offs becomes segment END) ----
__global__ __launch_bounds__(256) void k_fill(const int* __restrict__ edges,
                                              int* __restrict__ offs,
                                              int* __restrict__ elist) {
    const int e = blockIdx.x * 256 + threadIdx.x;
    if (e >= N_EDGES) return;
    const int s = edges[2 * e];
    const int t = edges[2 * e + 1];
    const int p = atomicAdd(&offs[t], 1);
    elist[p] = s;
}

// ---- single-pass online softmax + weighted fp16 h gather, 4 nodes/block ----
__global__ __launch_bounds__(256) void k_out(const __half* __restrict__ h,
                                             const int* __restrict__ elist,
                                             const float* __restrict__ f,
                                             const float* __restrict__ g,
                                             const int* __restrict__ offs, // segment END
                                             const int* __restrict__ counts,
                                             const float* __restrict__ bias,
                                             float* __restrict__ out) {
    const int n = blockIdx.x * 4 + (threadIdx.x >> 6);
    if (n >= N_NODES) return;
    const int lane = threadIdx.x & 63;
    const int head = lane >> 3;   // 8 lanes per head, 4 channels per lane
    const int end = offs[n];
    const int start = end - counts[n];
    const float fn = f[(size_t)n * HEADS + head];
    const int c4 = lane * 4;

    float m = -INFINITY, d = 0.f;
    float4 acc = make_float4(0.f, 0.f, 0.f, 0.f);

    // 2-deep pipeline: sB = src index one edge ahead of the g/h prefetch
    int p = start;
    float gz_n = 0.f;
    h4pk hv_n = {};
    int sB = 0;
    if (p < end) {
        const int sA = elist[p];
        gz_n = g[(size_t)sA * HEADS + head];
        hv_n = *reinterpret_cast<const h4pk*>(h + (size_t)sA * HU + c4);
        if (p + 1 < end) sB = elist[p + 1];
    }
    while (p < end) {
        const float gz = gz_n;
        const h4pk hv = hv_n;
        const int pn = p + 1;
        if (pn < end) {
            gz_n = g[(size_t)sB * HEADS + head];
            hv_n = *reinterpret_cast<const h4pk*>(h + (size_t)sB * HU + c4);
            if (pn + 1 < end) sB = elist[pn + 1];
        }
        float z = fn + gz;
        z = (z > 0.f) ? z : LEAKY * z;
        const float mn = fmaxf(m, z);
        const float c = __expf(m - mn);
        const float w = __expf(z - mn);
        m = mn;
        d = d * c + w;
        const float2 fa = __half22float2(hv.a);
        const float2 fb = __half22float2(hv.b);
        acc.x = acc.x * c + w * fa.x;
        acc.y = acc.y * c + w * fa.y;
        acc.z = acc.z * c + w * fb.x;
        acc.w = acc.w * c + w * fb.y;
        p = pn;
    }

    const float inv = 1.f / (d + EPSV);
    const float4 b = *reinterpret_cast<const float4*>(bias + c4);
    float v;
    float4 o;
    v = acc.x * inv + b.x; o.x = (v > 0.f) ? v : expm1f(v);
    v = acc.y * inv + b.y; o.y = (v > 0.f) ? v : expm1f(v);
    v = acc.z * inv + b.z; o.z = (v > 0.f) ? v : expm1f(v);
    v = acc.w * inv + b.w; o.w = (v > 0.f) ? v : expm1f(v);
    *reinterpret_cast<float4*>(out + (size_t)n * HU + c4) = o;
}

extern "C" void kernel_launch(void* const* d_in, const int* in_sizes, int n_in,
                              void* d_out, int out_size, void* d_ws, size_t ws_size,
                              hipStream_t stream) {
    const float* x = (const float*)d_in[0];
    const int* edges = (const int*)d_in[1];
    const float* W = (const float*)d_in[2];
    const float* ka1 = (const float*)d_in[3];
    // d_in[4] = ka2: unused by the reference
    const float* bias = (const float*)d_in[5];
    float* out = (float*)d_out;

    char* ws = (char*)d_ws;
    size_t off = 0;
    auto alloc = [&](size_t bytes) -> void* {
        void* p = ws + off;
        off = (off + bytes + 255) & ~size_t(255);
        return p;
    };
    __half* h = (__half*)alloc(sizeof(__half) * (size_t)N_NODES * HU); // 25.6 MB
    float* f = (float*)alloc(sizeof(float) * N_NODES * HEADS);         // 1.6 MB
    float* g = (float*)alloc(sizeof(float) * N_NODES * HEADS);         // 1.6 MB
    int* counts = (int*)alloc(sizeof(int) * N_NODES);
    int* offs = (int*)alloc(sizeof(int) * N_NODES);
    int* elist = (int*)alloc(sizeof(int) * N_EDGES);                   // 3.2 MB

    hipMemsetAsync(counts, 0, sizeof(int) * N_NODES, stream);

    k_gemm<<<N_NODES / NPB, 256, 0, stream>>>(x, W, ka1, h, f);
    k_pre<<<(N_EDGES + 255) / 256, 256, 0, stream>>>(edges, f, g, counts);
    k_scan<<<1, SCAN_T, 0, stream>>>(counts, offs);
    k_fill<<<(N_EDGES + 255) / 256, 256, 0, stream>>>(edges, offs, elist);
    k_out<<<(N_NODES + 3) / 4, 256, 0, stream>>>(h, elist, f, g, offs, counts, bias, out);
}

// Round 4
// 322.206 us; speedup vs baseline: 1.9750x; 1.0736x over previous
//
#include <hip/hip_runtime.h>
#include <hip/hip_fp16.h>

#define N_NODES 50000
#define N_EDGES 800000
#define D_FEAT 128
#define HEADS 8
#define UNITS 32
#define HU (HEADS * UNITS) /* 256 */
#define LEAKY 0.2f
#define EPSV 1e-7f

typedef _Float16 half8 __attribute__((ext_vector_type(8)));
typedef float f32x4 __attribute__((ext_vector_type(4)));

struct h4pk { __half2 a, b; }; // 4 fp16 channels = 8 bytes

// ---- fused: x fp32->fp16 | W -> W^T fp16 | in-degree counts ----
#define XBLK 3125             /* 3125*256*8 = 6,400,000 = N_NODES*D_FEAT */
#define WBLK 128              /* 128*256 = 32768 = D_FEAT*HU */
#define EBLK 3125             /* 3125*256 = 800,000 = N_EDGES */
__global__ __launch_bounds__(256) void k_conv(const float* __restrict__ x,
                                              const float* __restrict__ W,
                                              const int* __restrict__ edges,
                                              __half* __restrict__ x16,
                                              __half* __restrict__ Wt,
                                              int* __restrict__ counts) {
    const int b = blockIdx.x, t = threadIdx.x;
    if (b < XBLK) {
        const int i = (b * 256 + t) * 8;
        const float4 v0 = *reinterpret_cast<const float4*>(x + i);
        const float4 v1 = *reinterpret_cast<const float4*>(x + i + 4);
        half8 o;
        o[0] = (_Float16)v0.x; o[1] = (_Float16)v0.y;
        o[2] = (_Float16)v0.z; o[3] = (_Float16)v0.w;
        o[4] = (_Float16)v1.x; o[5] = (_Float16)v1.y;
        o[6] = (_Float16)v1.z; o[7] = (_Float16)v1.w;
        *reinterpret_cast<half8*>(x16 + i) = o;
    } else if (b < XBLK + WBLK) {
        const int i = (b - XBLK) * 256 + t;   // i = n*128 + k
        const int n = i >> 7, k = i & 127;
        Wt[i] = __float2half(W[k * HU + n]);  // Wt[n][k] = W[k][n]
    } else {
        const int e = (b - XBLK - WBLK) * 256 + t;
        if (e < N_EDGES) atomicAdd(&counts[edges[2 * e + 1]], 1);
    }
}

// ---- MFMA GEMM: h(fp16) = x16 @ Wt^T, fused f = sum(h*ka1, units) ----
// 1 wave per 16-row strip. A-frag: row=l&15, k=(l>>4)*8..+8 (contiguous).
// B-frag from Wt[col][k]: col=l&15, same k slice. C/D: col=l&15, row=(l>>4)*4+r.
__global__ __launch_bounds__(64) void k_gemm(const __half* __restrict__ x16,
                                             const __half* __restrict__ Wt,
                                             const float* __restrict__ ka1,
                                             __half* __restrict__ h,
                                             float* __restrict__ f) {
    __shared__ __align__(16) __half hs[16 * HU]; // 8 KB
    const int l = threadIdx.x;
    const int row16 = l & 15, kg = l >> 4;
    const size_t rbase = (size_t)blockIdx.x * 16;

    half8 a[4];
#pragma unroll
    for (int ks = 0; ks < 4; ++ks)
        a[ks] = *reinterpret_cast<const half8*>(x16 + (rbase + row16) * D_FEAT + ks * 32 + kg * 8);

    f32x4 acc[16];
#pragma unroll
    for (int ct = 0; ct < 16; ++ct) acc[ct] = (f32x4){0.f, 0.f, 0.f, 0.f};

#pragma unroll
    for (int ct = 0; ct < 16; ++ct) {
        const __half* wp = Wt + (ct * 16 + row16) * D_FEAT + kg * 8;
#pragma unroll
        for (int ks = 0; ks < 4; ++ks) {
            const half8 bf = *reinterpret_cast<const half8*>(wp + ks * 32);
            acc[ct] = __builtin_amdgcn_mfma_f32_16x16x32_f16(a[ks], bf, acc[ct], 0, 0, 0);
        }
    }

    // stage C tile to LDS (fp16)
#pragma unroll
    for (int ct = 0; ct < 16; ++ct) {
        const int col = ct * 16 + row16;
#pragma unroll
        for (int r = 0; r < 4; ++r)
            hs[(kg * 4 + r) * HU + col] = __float2half(acc[ct][r]);
    }
    __syncthreads();

    // coalesced h writeback: 16*256 fp16 = 8 KB = 8 iters of 1 KB
#pragma unroll
    for (int j = 0; j < 8; ++j) {
        const int slot = j * 64 + l;
        const half8 v = *reinterpret_cast<const half8*>(hs + slot * 8);
        *reinterpret_cast<half8*>(h + rbase * HU + slot * 8) = v;
    }

    // f[row][head] from staged tile: lane handles o = l and o+64 (o = row*8+head)
#pragma unroll
    for (int hf = 0; hf < 2; ++hf) {
        const int o = hf * 64 + l;
        const int row = o >> 3, hd = o & 7;
        const __half* hp = hs + row * HU + hd * UNITS;
        const float* kp = ka1 + hd * UNITS;
        float s = 0.f;
#pragma unroll
        for (int u = 0; u < UNITS; u += 8) {
            const half8 hv = *reinterpret_cast<const half8*>(hp + u);
            const float4 k0 = *reinterpret_cast<const float4*>(kp + u);
            const float4 k1 = *reinterpret_cast<const float4*>(kp + u + 4);
            s += (float)hv[0] * k0.x + (float)hv[1] * k0.y + (float)hv[2] * k0.z + (float)hv[3] * k0.w;
            s += (float)hv[4] * k1.x + (float)hv[5] * k1.y + (float)hv[6] * k1.z + (float)hv[7] * k1.w;
        }
        f[rbase * HEADS + o] = s; // contiguous across o
    }
}

// ---- single-block exclusive scan of counts -> offs ----
#define SCAN_T 1024
#define CHUNK 49 /* 1024*49 = 50176 >= 50000 */
__global__ __launch_bounds__(1024) void k_scan(const int* __restrict__ counts,
                                               int* __restrict__ offs) {
    __shared__ int sdata[SCAN_T];
    const int t = threadIdx.x;
    const int base = t * CHUNK;
    int sum = 0;
    for (int i = 0; i < CHUNK; ++i) {
        const int idx = base + i;
        if (idx < N_NODES) sum += counts[idx];
    }
    sdata[t] = sum;
    __syncthreads();
    for (int o = 1; o < SCAN_T; o <<= 1) {
        const int v = (t >= o) ? sdata[t - o] : 0;
        __syncthreads();
        sdata[t] += v;
        __syncthreads();
    }
    int run = (t > 0) ? sdata[t - 1] : 0;
    for (int i = 0; i < CHUNK; ++i) {
        const int idx = base + i;
        if (idx < N_NODES) {
            offs[idx] = run;
            run += counts[idx];
        }
    }
}

// ---- fused: g[v]=f[targets[v]] + CSR fill (offs becomes segment END) ----
__global__ __launch_bounds__(256) void k_fillg(const int* __restrict__ edges,
                                               const float* __restrict__ f,
                                               float* __restrict__ g,
                                               int* __restrict__ offs,
                                               int* __restrict__ elist) {
    const int i = blockIdx.x * 256 + threadIdx.x;
    if (i < N_NODES) {
        const int t2 = edges[2 * i + 1];
        const float4 A = *reinterpret_cast<const float4*>(f + (size_t)t2 * HEADS);
        const float4 B = *reinterpret_cast<const float4*>(f + (size_t)t2 * HEADS + 4);
        *reinterpret_cast<float4*>(g + (size_t)i * HEADS) = A;
        *reinterpret_cast<float4*>(g + (size_t)i * HEADS + 4) = B;
    }
    if (i < N_EDGES) {
        const int s = edges[2 * i];
        const int t = edges[2 * i + 1];
        const int p = atomicAdd(&offs[t], 1);
        elist[p] = s;
    }
}

// ---- single-pass online softmax + weighted fp16 h gather, 4 nodes/block ----
__global__ __launch_bounds__(256) void k_out(const __half* __restrict__ h,
                                             const int* __restrict__ elist,
                                             const float* __restrict__ f,
                                             const float* __restrict__ g,
                                             const int* __restrict__ offs, // segment END
                                             const int* __restrict__ counts,
                                             const float* __restrict__ bias,
                                             float* __restrict__ out) {
    const int n = blockIdx.x * 4 + (threadIdx.x >> 6);
    if (n >= N_NODES) return;
    const int lane = threadIdx.x & 63;
    const int head = lane >> 3;   // 8 lanes per head, 4 channels per lane
    const int end = offs[n];
    const int start = end - counts[n];
    const float fn = f[(size_t)n * HEADS + head];
    const int c4 = lane * 4;

    float m = -INFINITY, d = 0.f;
    float4 acc = make_float4(0.f, 0.f, 0.f, 0.f);

    int p = start;
    float gz_n = 0.f;
    h4pk hv_n = {};
    int sB = 0;
    if (p < end) {
        const int sA = elist[p];
        gz_n = g[(size_t)sA * HEADS + head];
        hv_n = *reinterpret_cast<const h4pk*>(h + (size_t)sA * HU + c4);
        if (p + 1 < end) sB = elist[p + 1];
    }
    while (p < end) {
        const float gz = gz_n;
        const h4pk hv = hv_n;
        const int pn = p + 1;
        if (pn < end) {
            gz_n = g[(size_t)sB * HEADS + head];
            hv_n = *reinterpret_cast<const h4pk*>(h + (size_t)sB * HU + c4);
            if (pn + 1 < end) sB = elist[pn + 1];
        }
        float z = fn + gz;
        z = (z > 0.f) ? z : LEAKY * z;
        const float mn = fmaxf(m, z);
        const float c = __expf(m - mn);
        const float w = __expf(z - mn);
        m = mn;
        d = d * c + w;
        const float2 fa = __half22float2(hv.a);
        const float2 fb = __half22float2(hv.b);
        acc.x = acc.x * c + w * fa.x;
        acc.y = acc.y * c + w * fa.y;
        acc.z = acc.z * c + w * fb.x;
        acc.w = acc.w * c + w * fb.y;
        p = pn;
    }

    const float inv = 1.f / (d + EPSV);
    const float4 b = *reinterpret_cast<const float4*>(bias + c4);
    float v;
    float4 o;
    v = acc.x * inv + b.x; o.x = (v > 0.f) ? v : expm1f(v);
    v = acc.y * inv + b.y; o.y = (v > 0.f) ? v : expm1f(v);
    v = acc.z * inv + b.z; o.z = (v > 0.f) ? v : expm1f(v);
    v = acc.w * inv + b.w; o.w = (v > 0.f) ? v : expm1f(v);
    *reinterpret_cast<float4*>(out + (size_t)n * HU + c4) = o;
}

extern "C" void kernel_launch(void* const* d_in, const int* in_sizes, int n_in,
                              void* d_out, int out_size, void* d_ws, size_t ws_size,
                              hipStream_t stream) {
    const float* x = (const float*)d_in[0];
    const int* edges = (const int*)d_in[1];
    const float* W = (const float*)d_in[2];
    const float* ka1 = (const float*)d_in[3];
    // d_in[4] = ka2: unused by the reference
    const float* bias = (const float*)d_in[5];
    float* out = (float*)d_out;

    char* ws = (char*)d_ws;
    size_t off = 0;
    auto alloc = [&](size_t bytes) -> void* {
        void* p = ws + off;
        off = (off + bytes + 255) & ~size_t(255);
        return p;
    };
    __half* h = (__half*)alloc(sizeof(__half) * (size_t)N_NODES * HU);     // 25.6 MB
    __half* x16 = (__half*)alloc(sizeof(__half) * (size_t)N_NODES * D_FEAT); // 12.8 MB
    __half* Wt = (__half*)alloc(sizeof(__half) * D_FEAT * HU);             // 64 KB
    float* f = (float*)alloc(sizeof(float) * N_NODES * HEADS);             // 1.6 MB
    float* g = (float*)alloc(sizeof(float) * N_NODES * HEADS);             // 1.6 MB
    int* counts = (int*)alloc(sizeof(int) * N_NODES);
    int* offs = (int*)alloc(sizeof(int) * N_NODES);
    int* elist = (int*)alloc(sizeof(int) * N_EDGES);                       // 3.2 MB

    hipMemsetAsync(counts, 0, sizeof(int) * N_NODES, stream);

    k_conv<<<XBLK + WBLK + EBLK, 256, 0, stream>>>(x, W, edges, x16, Wt, counts);
    k_gemm<<<N_NODES / 16, 64, 0, stream>>>(x16, Wt, ka1, h, f);
    k_scan<<<1, SCAN_T, 0, stream>>>(counts, offs);
    k_fillg<<<(N_EDGES + 255) / 256, 256, 0, stream>>>(edges, f, g, offs, elist);
    k_out<<<(N_NODES + 3) / 4, 256, 0, stream>>>(h, elist, f, g, offs, counts, bias, out);
}

// Round 5
// 229.524 us; speedup vs baseline: 2.7725x; 1.4038x over previous
//
#include <hip/hip_runtime.h>
#include <hip/hip_fp16.h>

#define N_NODES 50000
#define N_EDGES 800000
#define D_FEAT 128
#define HEADS 8
#define UNITS 32
#define HU (HEADS * UNITS) /* 256 */
#define LEAKY 0.2f
#define EPSV 1e-7f
#define NBLK 196 /* ceil(50000/256) */

typedef _Float16 half8 __attribute__((ext_vector_type(8)));
typedef float f32x4 __attribute__((ext_vector_type(4)));

struct h4pk { __half2 a, b; }; // 4 fp16 channels = 8 bytes

// ---- fused: x fp32->fp16 | W -> W^T fp16 | in-degree counts ----
#define XBLK 3125             /* 3125*256*8 = 6,400,000 = N_NODES*D_FEAT */
#define WBLK 128              /* 128*256 = 32768 = D_FEAT*HU */
#define EBLK 3125             /* 3125*256 = 800,000 = N_EDGES */
__global__ __launch_bounds__(256) void k_conv(const float* __restrict__ x,
                                              const float* __restrict__ W,
                                              const int* __restrict__ edges,
                                              __half* __restrict__ x16,
                                              __half* __restrict__ Wt,
                                              int* __restrict__ counts) {
    const int b = blockIdx.x, t = threadIdx.x;
    if (b < XBLK) {
        const int i = (b * 256 + t) * 8;
        const float4 v0 = *reinterpret_cast<const float4*>(x + i);
        const float4 v1 = *reinterpret_cast<const float4*>(x + i + 4);
        half8 o;
        o[0] = (_Float16)v0.x; o[1] = (_Float16)v0.y;
        o[2] = (_Float16)v0.z; o[3] = (_Float16)v0.w;
        o[4] = (_Float16)v1.x; o[5] = (_Float16)v1.y;
        o[6] = (_Float16)v1.z; o[7] = (_Float16)v1.w;
        *reinterpret_cast<half8*>(x16 + i) = o;
    } else if (b < XBLK + WBLK) {
        const int i = (b - XBLK) * 256 + t;   // i = n*128 + k
        const int n = i >> 7, k = i & 127;
        Wt[i] = __float2half(W[k * HU + n]);  // Wt[n][k] = W[k][n]
    } else {
        const int e = (b - XBLK - WBLK) * 256 + t;
        if (e < N_EDGES) atomicAdd(&counts[edges[2 * e + 1]], 1);
    }
}

// ---- MFMA GEMM: h(fp16) = x16 @ Wt^T, fused f = sum(h*ka1, units) ----
__global__ __launch_bounds__(64) void k_gemm(const __half* __restrict__ x16,
                                             const __half* __restrict__ Wt,
                                             const float* __restrict__ ka1,
                                             __half* __restrict__ h,
                                             float* __restrict__ f) {
    __shared__ __align__(16) __half hs[16 * HU]; // 8 KB
    const int l = threadIdx.x;
    const int row16 = l & 15, kg = l >> 4;
    const size_t rbase = (size_t)blockIdx.x * 16;

    half8 a[4];
#pragma unroll
    for (int ks = 0; ks < 4; ++ks)
        a[ks] = *reinterpret_cast<const half8*>(x16 + (rbase + row16) * D_FEAT + ks * 32 + kg * 8);

    f32x4 acc[16];
#pragma unroll
    for (int ct = 0; ct < 16; ++ct) acc[ct] = (f32x4){0.f, 0.f, 0.f, 0.f};

#pragma unroll
    for (int ct = 0; ct < 16; ++ct) {
        const __half* wp = Wt + (ct * 16 + row16) * D_FEAT + kg * 8;
#pragma unroll
        for (int ks = 0; ks < 4; ++ks) {
            const half8 bf = *reinterpret_cast<const half8*>(wp + ks * 32);
            acc[ct] = __builtin_amdgcn_mfma_f32_16x16x32_f16(a[ks], bf, acc[ct], 0, 0, 0);
        }
    }

#pragma unroll
    for (int ct = 0; ct < 16; ++ct) {
        const int col = ct * 16 + row16;
#pragma unroll
        for (int r = 0; r < 4; ++r)
            hs[(kg * 4 + r) * HU + col] = __float2half(acc[ct][r]);
    }
    __syncthreads();

#pragma unroll
    for (int j = 0; j < 8; ++j) {
        const int slot = j * 64 + l;
        const half8 v = *reinterpret_cast<const half8*>(hs + slot * 8);
        *reinterpret_cast<half8*>(h + rbase * HU + slot * 8) = v;
    }

#pragma unroll
    for (int hf = 0; hf < 2; ++hf) {
        const int o = hf * 64 + l;
        const int row = o >> 3, hd = o & 7;
        const __half* hp = hs + row * HU + hd * UNITS;
        const float* kp = ka1 + hd * UNITS;
        float s = 0.f;
#pragma unroll
        for (int u = 0; u < UNITS; u += 8) {
            const half8 hv = *reinterpret_cast<const half8*>(hp + u);
            const float4 k0 = *reinterpret_cast<const float4*>(kp + u);
            const float4 k1 = *reinterpret_cast<const float4*>(kp + u + 4);
            s += (float)hv[0] * k0.x + (float)hv[1] * k0.y + (float)hv[2] * k0.z + (float)hv[3] * k0.w;
            s += (float)hv[4] * k1.x + (float)hv[5] * k1.y + (float)hv[6] * k1.z + (float)hv[7] * k1.w;
        }
        f[rbase * HEADS + o] = s;
    }
}

// ---- hierarchical scan: A = block reduce, B = scan partials, C = block scan ----
__global__ __launch_bounds__(256) void k_scanA(const int* __restrict__ counts,
                                               int* __restrict__ partials) {
    const int i = blockIdx.x * 256 + threadIdx.x;
    int v = (i < N_NODES) ? counts[i] : 0;
#pragma unroll
    for (int m = 32; m >= 1; m >>= 1) v += __shfl_xor(v, m);
    __shared__ int ws[4];
    if ((threadIdx.x & 63) == 0) ws[threadIdx.x >> 6] = v;
    __syncthreads();
    if (threadIdx.x == 0) partials[blockIdx.x] = ws[0] + ws[1] + ws[2] + ws[3];
}

__global__ __launch_bounds__(256) void k_scanB(int* __restrict__ partials) {
    __shared__ int s[256];
    const int t = threadIdx.x;
    const int v = (t < NBLK) ? partials[t] : 0;
    s[t] = v;
    __syncthreads();
    for (int o = 1; o < 256; o <<= 1) {
        const int u = (t >= o) ? s[t - o] : 0;
        __syncthreads();
        s[t] += u;
        __syncthreads();
    }
    if (t < NBLK) partials[t] = s[t] - v; // exclusive
}

__global__ __launch_bounds__(256) void k_scanC(const int* __restrict__ counts,
                                               const int* __restrict__ partials,
                                               int* __restrict__ offs) {
    __shared__ int s[256];
    const int t = threadIdx.x;
    const int i = blockIdx.x * 256 + t;
    const int v = (i < N_NODES) ? counts[i] : 0;
    s[t] = v;
    __syncthreads();
    for (int o = 1; o < 256; o <<= 1) {
        const int u = (t >= o) ? s[t - o] : 0;
        __syncthreads();
        s[t] += u;
        __syncthreads();
    }
    if (i < N_NODES) offs[i] = partials[blockIdx.x] + s[t] - v; // exclusive
}

// ---- fused: g[v]=f[targets[v]] + CSR fill (offs becomes segment END) ----
__global__ __launch_bounds__(256) void k_fillg(const int* __restrict__ edges,
                                               const float* __restrict__ f,
                                               float* __restrict__ g,
                                               int* __restrict__ offs,
                                               int* __restrict__ elist) {
    const int i = blockIdx.x * 256 + threadIdx.x;
    if (i < N_NODES) {
        const int t2 = edges[2 * i + 1];
        const float4 A = *reinterpret_cast<const float4*>(f + (size_t)t2 * HEADS);
        const float4 B = *reinterpret_cast<const float4*>(f + (size_t)t2 * HEADS + 4);
        *reinterpret_cast<float4*>(g + (size_t)i * HEADS) = A;
        *reinterpret_cast<float4*>(g + (size_t)i * HEADS + 4) = B;
    }
    if (i < N_EDGES) {
        const int s = edges[2 * i];
        const int t = edges[2 * i + 1];
        const int p = atomicAdd(&offs[t], 1);
        elist[p] = s;
    }
}

// ---- single-pass online softmax + weighted fp16 h gather, 4 nodes/block ----
__global__ __launch_bounds__(256) void k_out(const __half* __restrict__ h,
                                             const int* __restrict__ elist,
                                             const float* __restrict__ f,
                                             const float* __restrict__ g,
                                             const int* __restrict__ offs, // segment END
                                             const int* __restrict__ counts,
                                             const float* __restrict__ bias,
                                             float* __restrict__ out) {
    const int n = blockIdx.x * 4 + (threadIdx.x >> 6);
    if (n >= N_NODES) return;
    const int lane = threadIdx.x & 63;
    const int head = lane >> 3;
    const int end = offs[n];
    const int start = end - counts[n];
    const float fn = f[(size_t)n * HEADS + head];
    const int c4 = lane * 4;

    float m = -INFINITY, d = 0.f;
    float4 acc = make_float4(0.f, 0.f, 0.f, 0.f);

    int p = start;
    float gz_n = 0.f;
    h4pk hv_n = {};
    int sB = 0;
    if (p < end) {
        const int sA = elist[p];
        gz_n = g[(size_t)sA * HEADS + head];
        hv_n = *reinterpret_cast<const h4pk*>(h + (size_t)sA * HU + c4);
        if (p + 1 < end) sB = elist[p + 1];
    }
    while (p < end) {
        const float gz = gz_n;
        const h4pk hv = hv_n;
        const int pn = p + 1;
        if (pn < end) {
            gz_n = g[(size_t)sB * HEADS + head];
            hv_n = *reinterpret_cast<const h4pk*>(h + (size_t)sB * HU + c4);
            if (pn + 1 < end) sB = elist[pn + 1];
        }
        float z = fn + gz;
        z = (z > 0.f) ? z : LEAKY * z;
        const float mn = fmaxf(m, z);
        const float c = __expf(m - mn);
        const float w = __expf(z - mn);
        m = mn;
        d = d * c + w;
        const float2 fa = __half22float2(hv.a);
        const float2 fb = __half22float2(hv.b);
        acc.x = acc.x * c + w * fa.x;
        acc.y = acc.y * c + w * fa.y;
        acc.z = acc.z * c + w * fb.x;
        acc.w = acc.w * c + w * fb.y;
        p = pn;
    }

    const float inv = 1.f / (d + EPSV);
    const float4 b = *reinterpret_cast<const float4*>(bias + c4);
    float v;
    float4 o;
    v = acc.x * inv + b.x; o.x = (v > 0.f) ? v : expm1f(v);
    v = acc.y * inv + b.y; o.y = (v > 0.f) ? v : expm1f(v);
    v = acc.z * inv + b.z; o.z = (v > 0.f) ? v : expm1f(v);
    v = acc.w * inv + b.w; o.w = (v > 0.f) ? v : expm1f(v);
    *reinterpret_cast<float4*>(out + (size_t)n * HU + c4) = o;
}

extern "C" void kernel_launch(void* const* d_in, const int* in_sizes, int n_in,
                              void* d_out, int out_size, void* d_ws, size_t ws_size,
                              hipStream_t stream) {
    const float* x = (const float*)d_in[0];
    const int* edges = (const int*)d_in[1];
    const float* W = (const float*)d_in[2];
    const float* ka1 = (const float*)d_in[3];
    // d_in[4] = ka2: unused by the reference
    const float* bias = (const float*)d_in[5];
    float* out = (float*)d_out;

    char* ws = (char*)d_ws;
    size_t off = 0;
    auto alloc = [&](size_t bytes) -> void* {
        void* p = ws + off;
        off = (off + bytes + 255) & ~size_t(255);
        return p;
    };
    __half* h = (__half*)alloc(sizeof(__half) * (size_t)N_NODES * HU);       // 25.6 MB
    __half* x16 = (__half*)alloc(sizeof(__half) * (size_t)N_NODES * D_FEAT); // 12.8 MB
    __half* Wt = (__half*)alloc(sizeof(__half) * D_FEAT * HU);               // 64 KB
    float* f = (float*)alloc(sizeof(float) * N_NODES * HEADS);               // 1.6 MB
    float* g = (float*)alloc(sizeof(float) * N_NODES * HEADS);               // 1.6 MB
    int* counts = (int*)alloc(sizeof(int) * N_NODES);
    int* offs = (int*)alloc(sizeof(int) * N_NODES);
    int* partials = (int*)alloc(sizeof(int) * NBLK);
    int* elist = (int*)alloc(sizeof(int) * N_EDGES);                         // 3.2 MB

    hipMemsetAsync(counts, 0, sizeof(int) * N_NODES, stream);

    k_conv<<<XBLK + WBLK + EBLK, 256, 0, stream>>>(x, W, edges, x16, Wt, counts);
    k_gemm<<<N_NODES / 16, 64, 0, stream>>>(x16, Wt, ka1, h, f);
    k_scanA<<<NBLK, 256, 0, stream>>>(counts, partials);
    k_scanB<<<1, 256, 0, stream>>>(partials);
    k_scanC<<<NBLK, 256, 0, stream>>>(counts, partials, offs);
    k_fillg<<<(N_EDGES + 255) / 256, 256, 0, stream>>>(edges, f, g, offs, elist);
    k_out<<<(N_NODES + 3) / 4, 256, 0, stream>>>(h, elist, f, g, offs, counts, bias, out);
}